// Round 1
// baseline (940.362 us; speedup 1.0000x reference)
//
#include <hip/hip_runtime.h>
#include <hip/hip_bf16.h>
#include <cstdint>
#include <cstdio>

#define NUM_T   8192
#define HDIM    1024
#define IDIM    4096
#define NEXP    8

#define BM      128
#define BN      128
#define BKS     64                 // K elems staged per LDS step
#define RBMAX   136                // ceil((16384 + 8*127)/128)
#define MAXROWS (RBMAX * BM)       // 17408 padded pair-rows

typedef __attribute__((ext_vector_type(8))) short short8;
typedef __attribute__((ext_vector_type(4))) float f32x4;

__device__ __forceinline__ unsigned short f32_to_bf16(float f) {
  uint32_t u = __float_as_uint(f);
  u += 0x7fffu + ((u >> 16) & 1u);   // RNE; inputs are finite
  return (unsigned short)(u >> 16);
}

// ---------------- fp32 -> bf16 bulk convert ----------------
__global__ void cvt_kernel(const float* __restrict__ in, unsigned short* __restrict__ out, int n4) {
  int i = blockIdx.x * blockDim.x + threadIdx.x;
  const int stride = gridDim.x * blockDim.x;
  for (; i < n4; i += stride) {
    const float4 v = ((const float4*)in)[i];
    ushort4 o;
    o.x = f32_to_bf16(v.x); o.y = f32_to_bf16(v.y);
    o.z = f32_to_bf16(v.z); o.w = f32_to_bf16(v.w);
    ((ushort4*)out)[i] = o;
  }
}

// ---------------- router: logits (fp32, exact), top-2 softmax, expert counts ----------------
__global__ void router_kernel(const float* __restrict__ x, const float* __restrict__ wg,
                              float* __restrict__ logits, int* __restrict__ tki,
                              float* __restrict__ tkg, int* __restrict__ counts) {
  const int t = blockIdx.x * 4 + (threadIdx.x >> 6);   // one wave per token
  const int lane = threadIdx.x & 63;
  const float* xr = x + (size_t)t * HDIM;
  float acc[NEXP];
#pragma unroll
  for (int e = 0; e < NEXP; ++e) acc[e] = 0.f;
  for (int h = lane; h < HDIM; h += 64) {
    const float xv = xr[h];
#pragma unroll
    for (int e = 0; e < NEXP; ++e) acc[e] += xv * wg[e * HDIM + h];
  }
#pragma unroll
  for (int e = 0; e < NEXP; ++e) {
#pragma unroll
    for (int s = 32; s > 0; s >>= 1) acc[e] += __shfl_xor(acc[e], s, 64);
  }
  if (lane == 0) {
    float v0 = -1e30f, v1 = -1e30f; int i0 = 0, i1 = 0;
#pragma unroll
    for (int e = 0; e < NEXP; ++e) {
      const float v = acc[e];
      logits[(size_t)t * NEXP + e] = v;
      if (v > v0)      { v1 = v0; i1 = i0; v0 = v; i0 = e; }
      else if (v > v1) { v1 = v; i1 = e; }
    }
    const float g0 = 1.f / (1.f + expf(v1 - v0));  // softmax over top-2
    tki[t * 2] = i0; tki[t * 2 + 1] = i1;
    tkg[t * 2] = g0; tkg[t * 2 + 1] = 1.f - g0;
    atomicAdd(&counts[i0], 1);
    atomicAdd(&counts[i1], 1);
  }
}

// ---------------- prefix sum with 128-alignment padding ----------------
__global__ void offsets_kernel(const int* __restrict__ counts, int* __restrict__ off) {
  if (threadIdx.x == 0 && blockIdx.x == 0) {
    int o = 0; off[0] = 0;
    for (int e = 0; e < NEXP; ++e) { o += (counts[e] + BM - 1) & ~(BM - 1); off[e + 1] = o; }
  }
}

// ---------------- scatter (token, gate) pairs into expert-grouped rows ----------------
__global__ void scatter_kernel(const int* __restrict__ tki, const float* __restrict__ tkg,
                               const int* __restrict__ off, int* __restrict__ fill,
                               int* __restrict__ ptok, float* __restrict__ pgate) {
  const int t = blockIdx.x * 256 + threadIdx.x;
  if (t >= NUM_T) return;
#pragma unroll
  for (int k = 0; k < 2; ++k) {
    const int e = tki[t * 2 + k];
    const int pos = off[e] + atomicAdd(&fill[e], 1);
    ptok[pos] = t;
    pgate[pos] = tkg[t * 2 + k];
  }
}

// ---------------- fc GEMM: act = gelu(X[perm] @ Wfc[e]^T), bf16 out ----------------
// 128x128 tile, BK=64, 4 waves (2x2 of 64x64), 16x16x32 bf16 MFMA.
// XOR chunk-swizzle: linear LDS dest for global_load_lds, inverse-swizzled global src,
// swizzled ds_read -> 2-way (free) bank conflicts.
__launch_bounds__(256)
__global__ void fc_gemm(const unsigned short* __restrict__ xb,
                        const unsigned short* __restrict__ wfcb,
                        const int* __restrict__ ptok,
                        const int* __restrict__ off,
                        unsigned short* __restrict__ act) {
  const int row0 = blockIdx.y * BM;
  if (row0 >= off[8]) return;
  int e = 0;
  while (row0 >= off[e + 1]) ++e;
  const int icol0 = blockIdx.x * BN;

  __shared__ __align__(16) unsigned short Alds[BM * BKS];
  __shared__ __align__(16) unsigned short Blds[BN * BKS];
  __shared__ int s_tok[BM];

  const int tid = threadIdx.x;
  if (tid < BM) s_tok[tid] = ptok[row0 + tid];
  __syncthreads();

  // 4 A-loads + 4 B-loads per thread per K-step. load id = p*256+tid:
  // r = id>>3 (tile row), phys chunk = id&7, src logical chunk = (id&7)^(r&7)
  const unsigned short* gA[4];
  const unsigned short* gB[4];
#pragma unroll
  for (int p = 0; p < 4; ++p) {
    const int id = p * 256 + tid;
    const int r = id >> 3;
    const int cs = (id & 7) ^ (r & 7);
    gA[p] = xb + (size_t)s_tok[r] * HDIM + cs * 8;
    gB[p] = wfcb + ((size_t)e * IDIM + icol0 + r) * HDIM + cs * 8;
  }

  const int lane = tid & 63;
  const int wid = tid >> 6;
  const int wr = wid >> 1;
  const int wc = wid & 1;

  int aaddr[4], baddr[4];  // byte offsets for kk=0; kk=1 is ^64
#pragma unroll
  for (int m = 0; m < 4; ++m) {
    const int row = wr * 64 + m * 16 + (lane & 15);
    aaddr[m] = row * (BKS * 2) + (((lane >> 4) ^ (row & 7)) * 16);
  }
#pragma unroll
  for (int n = 0; n < 4; ++n) {
    const int row = wc * 64 + n * 16 + (lane & 15);
    baddr[n] = row * (BKS * 2) + (((lane >> 4) ^ (row & 7)) * 16);
  }

  f32x4 acc[4][4];
#pragma unroll
  for (int m = 0; m < 4; ++m)
#pragma unroll
    for (int n = 0; n < 4; ++n) acc[m][n] = (f32x4){0.f, 0.f, 0.f, 0.f};

  for (int k0 = 0; k0 < HDIM; k0 += BKS) {
    __syncthreads();
#pragma unroll
    for (int p = 0; p < 4; ++p) {
      __builtin_amdgcn_global_load_lds(
          (const __attribute__((address_space(1))) void*)(gA[p] + k0),
          (__attribute__((address_space(3))) void*)((char*)Alds + (p * 256 + tid) * 16), 16, 0, 0);
      __builtin_amdgcn_global_load_lds(
          (const __attribute__((address_space(1))) void*)(gB[p] + k0),
          (__attribute__((address_space(3))) void*)((char*)Blds + (p * 256 + tid) * 16), 16, 0, 0);
    }
    __syncthreads();
#pragma unroll
    for (int kk = 0; kk < 2; ++kk) {
      short8 a[4], b[4];
#pragma unroll
      for (int m = 0; m < 4; ++m)
        a[m] = *(const short8*)((const char*)Alds + (aaddr[m] ^ (kk * 64)));
#pragma unroll
      for (int n = 0; n < 4; ++n)
        b[n] = *(const short8*)((const char*)Blds + (baddr[n] ^ (kk * 64)));
#pragma unroll
      for (int m = 0; m < 4; ++m)
#pragma unroll
        for (int n = 0; n < 4; ++n)
          acc[m][n] = __builtin_amdgcn_mfma_f32_16x16x32_bf16(a[m], b[n], acc[m][n], 0, 0, 0);
    }
  }

  // epilogue: exact gelu, bf16 store.  D: row=(lane>>4)*4+r, col=lane&15
#pragma unroll
  for (int m = 0; m < 4; ++m) {
    const int prow = row0 + wr * 64 + m * 16 + (lane >> 4) * 4;
#pragma unroll
    for (int n = 0; n < 4; ++n) {
      const int col = icol0 + wc * 64 + n * 16 + (lane & 15);
#pragma unroll
      for (int r = 0; r < 4; ++r) {
        const float v = acc[m][n][r];
        const float g = 0.5f * v * (1.0f + erff(v * 0.70710678118654752f));
        act[(size_t)(prow + r) * IDIM + col] = f32_to_bf16(g);
      }
    }
  }
}

// ---------------- proj GEMM: out[tok] += gate * (act @ Wproj[e]^T) ----------------
__launch_bounds__(256)
__global__ void proj_gemm(const unsigned short* __restrict__ actb,
                          const unsigned short* __restrict__ wpb,
                          const int* __restrict__ ptok,
                          const float* __restrict__ pgate,
                          const int* __restrict__ off,
                          float* __restrict__ out) {
  const int row0 = blockIdx.y * BM;
  if (row0 >= off[8]) return;
  int e = 0;
  while (row0 >= off[e + 1]) ++e;
  const int hcol0 = blockIdx.x * BN;

  __shared__ __align__(16) unsigned short Alds[BM * BKS];
  __shared__ __align__(16) unsigned short Blds[BN * BKS];
  __shared__ int s_tok[BM];
  __shared__ float s_g[BM];

  const int tid = threadIdx.x;
  if (tid < BM) { s_tok[tid] = ptok[row0 + tid]; s_g[tid] = pgate[row0 + tid]; }
  __syncthreads();

  const unsigned short* gA[4];
  const unsigned short* gB[4];
#pragma unroll
  for (int p = 0; p < 4; ++p) {
    const int id = p * 256 + tid;
    const int r = id >> 3;
    const int cs = (id & 7) ^ (r & 7);
    gA[p] = actb + (size_t)(row0 + r) * IDIM + cs * 8;
    gB[p] = wpb + ((size_t)e * HDIM + hcol0 + r) * IDIM + cs * 8;
  }

  const int lane = tid & 63;
  const int wid = tid >> 6;
  const int wr = wid >> 1;
  const int wc = wid & 1;

  int aaddr[4], baddr[4];
#pragma unroll
  for (int m = 0; m < 4; ++m) {
    const int row = wr * 64 + m * 16 + (lane & 15);
    aaddr[m] = row * (BKS * 2) + (((lane >> 4) ^ (row & 7)) * 16);
  }
#pragma unroll
  for (int n = 0; n < 4; ++n) {
    const int row = wc * 64 + n * 16 + (lane & 15);
    baddr[n] = row * (BKS * 2) + (((lane >> 4) ^ (row & 7)) * 16);
  }

  f32x4 acc[4][4];
#pragma unroll
  for (int m = 0; m < 4; ++m)
#pragma unroll
    for (int n = 0; n < 4; ++n) acc[m][n] = (f32x4){0.f, 0.f, 0.f, 0.f};

  for (int k0 = 0; k0 < IDIM; k0 += BKS) {
    __syncthreads();
#pragma unroll
    for (int p = 0; p < 4; ++p) {
      __builtin_amdgcn_global_load_lds(
          (const __attribute__((address_space(1))) void*)(gA[p] + k0),
          (__attribute__((address_space(3))) void*)((char*)Alds + (p * 256 + tid) * 16), 16, 0, 0);
      __builtin_amdgcn_global_load_lds(
          (const __attribute__((address_space(1))) void*)(gB[p] + k0),
          (__attribute__((address_space(3))) void*)((char*)Blds + (p * 256 + tid) * 16), 16, 0, 0);
    }
    __syncthreads();
#pragma unroll
    for (int kk = 0; kk < 2; ++kk) {
      short8 a[4], b[4];
#pragma unroll
      for (int m = 0; m < 4; ++m)
        a[m] = *(const short8*)((const char*)Alds + (aaddr[m] ^ (kk * 64)));
#pragma unroll
      for (int n = 0; n < 4; ++n)
        b[n] = *(const short8*)((const char*)Blds + (baddr[n] ^ (kk * 64)));
#pragma unroll
      for (int m = 0; m < 4; ++m)
#pragma unroll
        for (int n = 0; n < 4; ++n)
          acc[m][n] = __builtin_amdgcn_mfma_f32_16x16x32_bf16(a[m], b[n], acc[m][n], 0, 0, 0);
    }
  }

  // epilogue: scale by gate, scatter-add into out (pads have gate 0)
#pragma unroll
  for (int m = 0; m < 4; ++m) {
    const int lr = wr * 64 + m * 16 + (lane >> 4) * 4;
#pragma unroll
    for (int n = 0; n < 4; ++n) {
      const int col = hcol0 + wc * 64 + n * 16 + (lane & 15);
#pragma unroll
      for (int r = 0; r < 4; ++r) {
        const int tok = s_tok[lr + r];
        const float g = s_g[lr + r];
        atomicAdd(&out[(size_t)tok * HDIM + col], g * acc[m][n][r]);
      }
    }
  }
}

extern "C" void kernel_launch(void* const* d_in, const int* in_sizes, int n_in,
                              void* d_out, int out_size, void* d_ws, size_t ws_size,
                              hipStream_t stream) {
  const float* x   = (const float*)d_in[0];
  const float* wg  = (const float*)d_in[1];
  const float* wfc = (const float*)d_in[2];
  const float* wpj = (const float*)d_in[3];
  float* out    = (float*)d_out;
  float* logits = out + (size_t)NUM_T * HDIM;

  char* p = (char*)d_ws;
  auto alloc = [&](size_t bytes) { char* q = p; p += (bytes + 255) & ~size_t(255); return q; };
  unsigned short* xb    = (unsigned short*)alloc((size_t)NUM_T * HDIM * 2);
  unsigned short* wfcb  = (unsigned short*)alloc((size_t)NEXP * IDIM * HDIM * 2);
  unsigned short* wpb   = (unsigned short*)alloc((size_t)NEXP * HDIM * IDIM * 2);
  unsigned short* act   = (unsigned short*)alloc((size_t)MAXROWS * IDIM * 2);
  int*            ptok  = (int*)alloc((size_t)MAXROWS * 4);
  float*          pgate = (float*)alloc((size_t)MAXROWS * 4);
  int*            tki   = (int*)alloc((size_t)NUM_T * 2 * 4);
  float*          tkg   = (float*)alloc((size_t)NUM_T * 2 * 4);
  int*            counts= (int*)alloc(64);
  int*            fill  = (int*)alloc(64);
  int*            off   = (int*)alloc(64);
  const size_t need = (size_t)(p - (char*)d_ws);
  if (need > ws_size) {
    fprintf(stderr, "kernel_launch: ws too small: need %zu have %zu\n", need, ws_size);
    hipMemsetAsync(d_out, 0, (size_t)out_size * 4, stream);
    return;
  }

  // zero: output accum region, and [ptok .. off] aux region (pads -> token 0 / gate 0)
  hipMemsetAsync(out, 0, (size_t)NUM_T * HDIM * 4, stream);
  hipMemsetAsync(ptok, 0, (size_t)(p - (char*)ptok), stream);

  cvt_kernel<<<2048, 256, 0, stream>>>(x,   xb,   NUM_T * HDIM / 4);
  cvt_kernel<<<2048, 256, 0, stream>>>(wfc, wfcb, NEXP * IDIM * HDIM / 4);
  cvt_kernel<<<2048, 256, 0, stream>>>(wpj, wpb,  NEXP * HDIM * IDIM / 4);

  router_kernel<<<NUM_T / 4, 256, 0, stream>>>(x, wg, logits, tki, tkg, counts);
  offsets_kernel<<<1, 64, 0, stream>>>(counts, off);
  scatter_kernel<<<NUM_T / 256, 256, 0, stream>>>(tki, tkg, off, fill, ptok, pgate);

  fc_gemm<<<dim3(IDIM / BN, RBMAX), 256, 0, stream>>>(xb, wfcb, ptok, off, act);
  proj_gemm<<<dim3(HDIM / BN, RBMAX), 256, 0, stream>>>(act, wpb, ptok, pgate, off, out);
}

// Round 2
// 911.157 us; speedup vs baseline: 1.0321x; 1.0321x over previous
//
#include <hip/hip_runtime.h>
#include <hip/hip_bf16.h>
#include <cstdint>
#include <cstdio>

#define NUM_T   8192
#define HDIM    1024
#define IDIM    4096
#define NEXP    8

#define ALGN    256                 // expert group alignment (= fc tile M)
#define RB_FC   72                  // ceil((16384 + 8*255)/256)
#define RB_PJ   144                 // same rows in 128-tiles
#define MAXROWS (RB_FC * 256)       // 18432 padded pair-rows

typedef __attribute__((ext_vector_type(8))) short short8;
typedef __attribute__((ext_vector_type(4))) float f32x4;

__device__ __forceinline__ unsigned short f32_to_bf16(float f) {
  uint32_t u = __float_as_uint(f);
  u += 0x7fffu + ((u >> 16) & 1u);   // RNE; inputs are finite
  return (unsigned short)(u >> 16);
}
__device__ __forceinline__ float bf16_to_f32(unsigned short u) {
  return __uint_as_float(((uint32_t)u) << 16);
}
// bijective XCD swizzle: launch-order bid -> logical wgid, 8 contiguous chunks
__device__ __forceinline__ int xcd_swz(int bid, int nwg) {
  const int q = nwg >> 3, r = nwg & 7;
  const int x = bid & 7, i = bid >> 3;
  return (x < r ? x * (q + 1) : r * (q + 1) + (x - r) * q) + i;
}

// ---------------- fp32 -> bf16 bulk convert ----------------
__global__ void cvt_kernel(const float* __restrict__ in, unsigned short* __restrict__ out, int n4) {
  int i = blockIdx.x * blockDim.x + threadIdx.x;
  const int stride = gridDim.x * blockDim.x;
  for (; i < n4; i += stride) {
    const float4 v = ((const float4*)in)[i];
    ushort4 o;
    o.x = f32_to_bf16(v.x); o.y = f32_to_bf16(v.y);
    o.z = f32_to_bf16(v.z); o.w = f32_to_bf16(v.w);
    ((ushort4*)out)[i] = o;
  }
}

// ---------------- router: logits (fp32, exact), top-2 softmax, expert counts ----------------
__global__ void router_kernel(const float* __restrict__ x, const float* __restrict__ wg,
                              float* __restrict__ logits, int* __restrict__ tki,
                              float* __restrict__ tkg, int* __restrict__ counts) {
  const int t = blockIdx.x * 4 + (threadIdx.x >> 6);   // one wave per token
  const int lane = threadIdx.x & 63;
  const float* xr = x + (size_t)t * HDIM;
  float acc[NEXP];
#pragma unroll
  for (int e = 0; e < NEXP; ++e) acc[e] = 0.f;
  for (int h = lane; h < HDIM; h += 64) {
    const float xv = xr[h];
#pragma unroll
    for (int e = 0; e < NEXP; ++e) acc[e] += xv * wg[e * HDIM + h];
  }
#pragma unroll
  for (int e = 0; e < NEXP; ++e) {
#pragma unroll
    for (int s = 32; s > 0; s >>= 1) acc[e] += __shfl_xor(acc[e], s, 64);
  }
  if (lane == 0) {
    float v0 = -1e30f, v1 = -1e30f; int i0 = 0, i1 = 0;
#pragma unroll
    for (int e = 0; e < NEXP; ++e) {
      const float v = acc[e];
      logits[(size_t)t * NEXP + e] = v;
      if (v > v0)      { v1 = v0; i1 = i0; v0 = v; i0 = e; }
      else if (v > v1) { v1 = v; i1 = e; }
    }
    const float g0 = 1.f / (1.f + expf(v1 - v0));  // softmax over top-2
    tki[t * 2] = i0; tki[t * 2 + 1] = i1;
    tkg[t * 2] = g0; tkg[t * 2 + 1] = 1.f - g0;
    atomicAdd(&counts[i0], 1);
    atomicAdd(&counts[i1], 1);
  }
}

// ---------------- prefix sum with 256-alignment padding ----------------
__global__ void offsets_kernel(const int* __restrict__ counts, int* __restrict__ off) {
  if (threadIdx.x == 0 && blockIdx.x == 0) {
    int o = 0; off[0] = 0;
    for (int e = 0; e < NEXP; ++e) { o += (counts[e] + ALGN - 1) & ~(ALGN - 1); off[e + 1] = o; }
  }
}

// ---------------- scatter (token, gate) pairs into expert-grouped rows; inverse map ----------------
__global__ void scatter_kernel(const int* __restrict__ tki, const float* __restrict__ tkg,
                               const int* __restrict__ off, int* __restrict__ fill,
                               int* __restrict__ ptok, float* __restrict__ pgate,
                               int* __restrict__ inv) {
  const int t = blockIdx.x * 256 + threadIdx.x;
  if (t >= NUM_T) return;
#pragma unroll
  for (int k = 0; k < 2; ++k) {
    const int e = tki[t * 2 + k];
    const int pos = off[e] + atomicAdd(&fill[e], 1);
    ptok[pos] = t;
    pgate[pos] = tkg[t * 2 + k];
    inv[t * 2 + k] = pos;
  }
}

// ---------------- fc GEMM: act = gelu(X[perm] @ Wfc[e]^T), bf16 out ----------------
// 256x256 tile, BK=64, 8 waves (2M x 4N of 128x64), double-buffered LDS,
// single barrier per K-step (stage next tile issued BEFORE compute -> overlap).
// XOR chunk-swizzle: linear LDS dest, inverse-swizzled global src, swizzled ds_read.
__launch_bounds__(512)
__global__ void fc_gemm(const unsigned short* __restrict__ xb,
                        const unsigned short* __restrict__ wfcb,
                        const int* __restrict__ ptok,
                        const int* __restrict__ off,
                        unsigned short* __restrict__ act) {
  const int nwg = (IDIM / 256) * RB_FC;
  const int wgid = xcd_swz(blockIdx.x, nwg);
  const int row0 = (wgid / (IDIM / 256)) * 256;
  const int icol0 = (wgid % (IDIM / 256)) * 256;
  if (row0 >= off[8]) return;
  int e = 0;
  while (row0 >= off[e + 1]) ++e;

  __shared__ __align__(16) unsigned short Al[2][256 * 64];
  __shared__ __align__(16) unsigned short Bl[2][256 * 64];
  __shared__ int s_tok[256];

  const int tid = threadIdx.x;
  if (tid < 256) s_tok[tid] = ptok[row0 + tid];
  __syncthreads();

  // staging: 4 A-loads + 4 B-loads per thread per K-step (16B each)
  const unsigned short* gA[4];
  const unsigned short* gB[4];
#pragma unroll
  for (int p = 0; p < 4; ++p) {
    const int id = p * 512 + tid;
    const int r = id >> 3;
    const int cs = (id & 7) ^ (r & 7);
    gA[p] = xb + (size_t)s_tok[r] * HDIM + cs * 8;
    gB[p] = wfcb + ((size_t)e * IDIM + icol0 + r) * HDIM + cs * 8;
  }

  const int lane = tid & 63;
  const int wid = tid >> 6;
  const int wr = wid >> 2;        // 0..1 (128 rows each)
  const int wc = wid & 3;         // 0..3 (64 cols each)

  int aaddr[8], baddr[4];          // byte offsets (kk=0); kk=1 is ^64
#pragma unroll
  for (int m = 0; m < 8; ++m) {
    const int row = wr * 128 + m * 16 + (lane & 15);
    aaddr[m] = row * 128 + (((lane >> 4) ^ (row & 7)) * 16);
  }
#pragma unroll
  for (int n = 0; n < 4; ++n) {
    const int row = wc * 64 + n * 16 + (lane & 15);
    baddr[n] = row * 128 + (((lane >> 4) ^ (row & 7)) * 16);
  }

  f32x4 acc[8][4];
#pragma unroll
  for (int m = 0; m < 8; ++m)
#pragma unroll
    for (int n = 0; n < 4; ++n) acc[m][n] = (f32x4){0.f, 0.f, 0.f, 0.f};

  const int NS = HDIM / 64;
  int cur = 0;
  // prologue: stage step 0 into buf0
#pragma unroll
  for (int p = 0; p < 4; ++p) {
    const int id = p * 512 + tid;
    __builtin_amdgcn_global_load_lds(
        (const __attribute__((address_space(1))) void*)(gA[p]),
        (__attribute__((address_space(3))) void*)((char*)&Al[0][0] + id * 16), 16, 0, 0);
    __builtin_amdgcn_global_load_lds(
        (const __attribute__((address_space(1))) void*)(gB[p]),
        (__attribute__((address_space(3))) void*)((char*)&Bl[0][0] + id * 16), 16, 0, 0);
  }

  for (int s = 0; s < NS; ++s) {
    __syncthreads();               // drains vmcnt: buf[cur] staged; prev reads done
    if (s + 1 < NS) {
      const int k0 = (s + 1) * 64;
#pragma unroll
      for (int p = 0; p < 4; ++p) {
        const int id = p * 512 + tid;
        __builtin_amdgcn_global_load_lds(
            (const __attribute__((address_space(1))) void*)(gA[p] + k0),
            (__attribute__((address_space(3))) void*)((char*)&Al[cur ^ 1][0] + id * 16), 16, 0, 0);
        __builtin_amdgcn_global_load_lds(
            (const __attribute__((address_space(1))) void*)(gB[p] + k0),
            (__attribute__((address_space(3))) void*)((char*)&Bl[cur ^ 1][0] + id * 16), 16, 0, 0);
      }
    }
    const char* Ab = (const char*)&Al[cur][0];
    const char* Bb = (const char*)&Bl[cur][0];
#pragma unroll
    for (int kk = 0; kk < 2; ++kk) {
      short8 a[8], b[4];
#pragma unroll
      for (int m = 0; m < 8; ++m) a[m] = *(const short8*)(Ab + (aaddr[m] ^ (kk * 64)));
#pragma unroll
      for (int n = 0; n < 4; ++n) b[n] = *(const short8*)(Bb + (baddr[n] ^ (kk * 64)));
#pragma unroll
      for (int m = 0; m < 8; ++m)
#pragma unroll
        for (int n = 0; n < 4; ++n)
          acc[m][n] = __builtin_amdgcn_mfma_f32_16x16x32_bf16(a[m], b[n], acc[m][n], 0, 0, 0);
    }
    cur ^= 1;
  }

  // epilogue: exact gelu, bf16 store.  D: row=(lane>>4)*4+r, col=lane&15
#pragma unroll
  for (int m = 0; m < 8; ++m) {
    const int prow = row0 + wr * 128 + m * 16 + (lane >> 4) * 4;
#pragma unroll
    for (int n = 0; n < 4; ++n) {
      const int col = icol0 + wc * 64 + n * 16 + (lane & 15);
#pragma unroll
      for (int r = 0; r < 4; ++r) {
        const float v = acc[m][n][r];
        const float g = 0.5f * v * (1.0f + erff(v * 0.70710678118654752f));
        act[(size_t)(prow + r) * IDIM + col] = f32_to_bf16(g);
      }
    }
  }
}

// ---------------- proj GEMM: pair[row] = gate * (act[row] @ Wproj[e]^T), bf16 ----------------
// 128x128 tile, BK=64, 4 waves, double-buffered LDS (64KB -> 2 blocks/CU),
// single barrier per K-step. No atomics: plain bf16 stores into pair rows.
__launch_bounds__(256)
__global__ void proj_gemm(const unsigned short* __restrict__ actb,
                          const unsigned short* __restrict__ wpb,
                          const float* __restrict__ pgate,
                          const int* __restrict__ off,
                          unsigned short* __restrict__ pair) {
  const int nwg = (HDIM / 128) * RB_PJ;
  const int wgid = xcd_swz(blockIdx.x, nwg);
  const int row0 = (wgid / (HDIM / 128)) * 128;
  const int hcol0 = (wgid % (HDIM / 128)) * 128;
  if (row0 >= off[8]) return;
  int e = 0;
  while (row0 >= off[e + 1]) ++e;

  __shared__ __align__(16) unsigned short Al[2][128 * 64];
  __shared__ __align__(16) unsigned short Bl[2][128 * 64];
  __shared__ float s_g[128];

  const int tid = threadIdx.x;
  if (tid < 128) s_g[tid] = pgate[row0 + tid];

  const unsigned short* gA[4];
  const unsigned short* gB[4];
#pragma unroll
  for (int p = 0; p < 4; ++p) {
    const int id = p * 256 + tid;
    const int r = id >> 3;
    const int cs = (id & 7) ^ (r & 7);
    gA[p] = actb + (size_t)(row0 + r) * IDIM + cs * 8;
    gB[p] = wpb + ((size_t)e * HDIM + hcol0 + r) * IDIM + cs * 8;
  }

  const int lane = tid & 63;
  const int wid = tid >> 6;
  const int wr = wid >> 1;
  const int wc = wid & 1;

  int aaddr[4], baddr[4];
#pragma unroll
  for (int m = 0; m < 4; ++m) {
    const int row = wr * 64 + m * 16 + (lane & 15);
    aaddr[m] = row * 128 + (((lane >> 4) ^ (row & 7)) * 16);
  }
#pragma unroll
  for (int n = 0; n < 4; ++n) {
    const int row = wc * 64 + n * 16 + (lane & 15);
    baddr[n] = row * 128 + (((lane >> 4) ^ (row & 7)) * 16);
  }

  f32x4 acc[4][4];
#pragma unroll
  for (int m = 0; m < 4; ++m)
#pragma unroll
    for (int n = 0; n < 4; ++n) acc[m][n] = (f32x4){0.f, 0.f, 0.f, 0.f};

  const int NS = IDIM / 64;
  int cur = 0;
#pragma unroll
  for (int p = 0; p < 4; ++p) {
    const int id = p * 256 + tid;
    __builtin_amdgcn_global_load_lds(
        (const __attribute__((address_space(1))) void*)(gA[p]),
        (__attribute__((address_space(3))) void*)((char*)&Al[0][0] + id * 16), 16, 0, 0);
    __builtin_amdgcn_global_load_lds(
        (const __attribute__((address_space(1))) void*)(gB[p]),
        (__attribute__((address_space(3))) void*)((char*)&Bl[0][0] + id * 16), 16, 0, 0);
  }

  for (int s = 0; s < NS; ++s) {
    __syncthreads();
    if (s + 1 < NS) {
      const int k0 = (s + 1) * 64;
#pragma unroll
      for (int p = 0; p < 4; ++p) {
        const int id = p * 256 + tid;
        __builtin_amdgcn_global_load_lds(
            (const __attribute__((address_space(1))) void*)(gA[p] + k0),
            (__attribute__((address_space(3))) void*)((char*)&Al[cur ^ 1][0] + id * 16), 16, 0, 0);
        __builtin_amdgcn_global_load_lds(
            (const __attribute__((address_space(1))) void*)(gB[p] + k0),
            (__attribute__((address_space(3))) void*)((char*)&Bl[cur ^ 1][0] + id * 16), 16, 0, 0);
      }
    }
    const char* Ab = (const char*)&Al[cur][0];
    const char* Bb = (const char*)&Bl[cur][0];
#pragma unroll
    for (int kk = 0; kk < 2; ++kk) {
      short8 a[4], b[4];
#pragma unroll
      for (int m = 0; m < 4; ++m) a[m] = *(const short8*)(Ab + (aaddr[m] ^ (kk * 64)));
#pragma unroll
      for (int n = 0; n < 4; ++n) b[n] = *(const short8*)(Bb + (baddr[n] ^ (kk * 64)));
#pragma unroll
      for (int m = 0; m < 4; ++m)
#pragma unroll
        for (int n = 0; n < 4; ++n)
          acc[m][n] = __builtin_amdgcn_mfma_f32_16x16x32_bf16(a[m], b[n], acc[m][n], 0, 0, 0);
    }
    cur ^= 1;
  }

  // epilogue: scale by gate, bf16 store into pair rows (pads have gate 0)
#pragma unroll
  for (int m = 0; m < 4; ++m) {
    const int lr = wr * 64 + m * 16 + (lane >> 4) * 4;
#pragma unroll
    for (int n = 0; n < 4; ++n) {
      const int col = hcol0 + wc * 64 + n * 16 + (lane & 15);
#pragma unroll
      for (int r = 0; r < 4; ++r) {
        const float g = s_g[lr + r];
        pair[(size_t)(row0 + lr + r) * HDIM + col] = f32_to_bf16(g * acc[m][n][r]);
      }
    }
  }
}

// ---------------- combine: out[t] = pair[inv[t,0]] + pair[inv[t,1]] (fp32 out) ----------------
__global__ void combine_kernel(const unsigned short* __restrict__ pair,
                               const int* __restrict__ inv, float* __restrict__ out) {
  const int gid = blockIdx.x * 256 + threadIdx.x;     // NUM_T*HDIM/8 threads
  const int t = gid >> 7;
  const int c8 = (gid & 127) << 3;
  const short8 v0 = *(const short8*)(pair + (size_t)inv[t * 2] * HDIM + c8);
  const short8 v1 = *(const short8*)(pair + (size_t)inv[t * 2 + 1] * HDIM + c8);
  float o[8];
#pragma unroll
  for (int j = 0; j < 8; ++j)
    o[j] = bf16_to_f32((unsigned short)v0[j]) + bf16_to_f32((unsigned short)v1[j]);
  float* dst = out + (size_t)t * HDIM + c8;
  ((float4*)dst)[0] = (float4){o[0], o[1], o[2], o[3]};
  ((float4*)dst)[1] = (float4){o[4], o[5], o[6], o[7]};
}

extern "C" void kernel_launch(void* const* d_in, const int* in_sizes, int n_in,
                              void* d_out, int out_size, void* d_ws, size_t ws_size,
                              hipStream_t stream) {
  const float* x   = (const float*)d_in[0];
  const float* wg  = (const float*)d_in[1];
  const float* wfc = (const float*)d_in[2];
  const float* wpj = (const float*)d_in[3];
  float* out    = (float*)d_out;
  float* logits = out + (size_t)NUM_T * HDIM;

  char* p = (char*)d_ws;
  auto alloc = [&](size_t bytes) { char* q = p; p += (bytes + 255) & ~size_t(255); return q; };
  unsigned short* xb    = (unsigned short*)alloc((size_t)NUM_T * HDIM * 2);
  unsigned short* wfcb  = (unsigned short*)alloc((size_t)NEXP * IDIM * HDIM * 2);
  unsigned short* wpb   = (unsigned short*)alloc((size_t)NEXP * HDIM * IDIM * 2);
  unsigned short* act   = (unsigned short*)alloc((size_t)MAXROWS * IDIM * 2);
  unsigned short* pair  = (unsigned short*)alloc((size_t)MAXROWS * HDIM * 2);
  int*            ptok  = (int*)alloc((size_t)MAXROWS * 4);
  float*          pgate = (float*)alloc((size_t)MAXROWS * 4);
  int*            tki   = (int*)alloc((size_t)NUM_T * 2 * 4);
  float*          tkg   = (float*)alloc((size_t)NUM_T * 2 * 4);
  int*            inv   = (int*)alloc((size_t)NUM_T * 2 * 4);
  int*            counts= (int*)alloc(64);
  int*            fill  = (int*)alloc(64);
  int*            off   = (int*)alloc(64);
  const size_t need = (size_t)(p - (char*)d_ws);
  if (need > ws_size) {
    fprintf(stderr, "kernel_launch: ws too small: need %zu have %zu\n", need, ws_size);
    hipMemsetAsync(d_out, 0, (size_t)out_size * 4, stream);
    return;
  }

  // zero aux region (pads -> token 0 / gate 0; counts/fill for atomics)
  hipMemsetAsync(ptok, 0, (size_t)(p - (char*)ptok), stream);

  cvt_kernel<<<2048, 256, 0, stream>>>(x,   xb,   NUM_T * HDIM / 4);
  cvt_kernel<<<2048, 256, 0, stream>>>(wfc, wfcb, NEXP * IDIM * HDIM / 4);
  cvt_kernel<<<2048, 256, 0, stream>>>(wpj, wpb,  NEXP * HDIM * IDIM / 4);

  router_kernel<<<NUM_T / 4, 256, 0, stream>>>(x, wg, logits, tki, tkg, counts);
  offsets_kernel<<<1, 64, 0, stream>>>(counts, off);
  scatter_kernel<<<NUM_T / 256, 256, 0, stream>>>(tki, tkg, off, fill, ptok, pgate, inv);

  fc_gemm<<<(IDIM / 256) * RB_FC, 512, 0, stream>>>(xb, wfcb, ptok, off, act);
  proj_gemm<<<(HDIM / 128) * RB_PJ, 256, 0, stream>>>(act, wpb, pgate, off, pair);
  combine_kernel<<<NUM_T * HDIM / 8 / 256, 256, 0, stream>>>(pair, inv, out);
}

// Round 3
// 857.675 us; speedup vs baseline: 1.0964x; 1.0624x over previous
//
#include <hip/hip_runtime.h>
#include <hip/hip_bf16.h>
#include <cstdint>
#include <cstdio>

#define NUM_T   8192
#define HDIM    1024
#define IDIM    4096
#define NEXP    8

#define ALGN    256                 // expert group alignment (= fc tile M)
#define RB_FC   72                  // ceil((16384 + 8*255)/256)
#define RB_PJ   144                 // same rows in 128-tiles
#define MAXROWS (RB_FC * 256)       // 18432 padded pair-rows

#define FC_NT   (HDIM / 64)         // 16 K-tiles
#define FC_NI   (FC_NT / 2)         // 8 iterations
#define PJ_NT   (IDIM / 64)         // 64 K-tiles
#define PJ_NI   (PJ_NT / 2)         // 32 iterations

typedef __attribute__((ext_vector_type(8))) short short8;
typedef __attribute__((ext_vector_type(4))) float f32x4;

__device__ __forceinline__ unsigned short f32_to_bf16(float f) {
  uint32_t u = __float_as_uint(f);
  u += 0x7fffu + ((u >> 16) & 1u);   // RNE; inputs are finite
  return (unsigned short)(u >> 16);
}
__device__ __forceinline__ float bf16_to_f32(unsigned short u) {
  return __uint_as_float(((uint32_t)u) << 16);
}
// bijective XCD swizzle: launch-order bid -> logical wgid, 8 contiguous chunks
__device__ __forceinline__ int xcd_swz(int bid, int nwg) {
  const int q = nwg >> 3, r = nwg & 7;
  const int x = bid & 7, i = bid >> 3;
  return (x < r ? x * (q + 1) : r * (q + 1) + (x - r) * q) + i;
}

#define GL16(srcp, ldsoff) __builtin_amdgcn_global_load_lds( \
    (const __attribute__((address_space(1))) void*)(srcp), \
    (__attribute__((address_space(3))) void*)(Lb + (ldsoff)), 16, 0, 0)

#define PHASE_SYNC() do { __builtin_amdgcn_s_barrier(); \
    asm volatile("s_waitcnt lgkmcnt(0)" ::: "memory"); \
    __builtin_amdgcn_sched_barrier(0); } while (0)
#define PHASE_END() __builtin_amdgcn_s_barrier()
#define VMW(n) asm volatile("s_waitcnt vmcnt(" #n ")" ::: "memory")

// ---------------- fp32 -> bf16 bulk convert ----------------
__global__ void cvt_kernel(const float* __restrict__ in, unsigned short* __restrict__ out, int n4) {
  int i = blockIdx.x * blockDim.x + threadIdx.x;
  const int stride = gridDim.x * blockDim.x;
  for (; i < n4; i += stride) {
    const float4 v = ((const float4*)in)[i];
    ushort4 o;
    o.x = f32_to_bf16(v.x); o.y = f32_to_bf16(v.y);
    o.z = f32_to_bf16(v.z); o.w = f32_to_bf16(v.w);
    ((ushort4*)out)[i] = o;
  }
}

// ---------------- router ----------------
__global__ void router_kernel(const float* __restrict__ x, const float* __restrict__ wg,
                              float* __restrict__ logits, int* __restrict__ tki,
                              float* __restrict__ tkg, int* __restrict__ counts) {
  const int t = blockIdx.x * 4 + (threadIdx.x >> 6);   // one wave per token
  const int lane = threadIdx.x & 63;
  const float* xr = x + (size_t)t * HDIM;
  float acc[NEXP];
#pragma unroll
  for (int e = 0; e < NEXP; ++e) acc[e] = 0.f;
  for (int h = lane; h < HDIM; h += 64) {
    const float xv = xr[h];
#pragma unroll
    for (int e = 0; e < NEXP; ++e) acc[e] += xv * wg[e * HDIM + h];
  }
#pragma unroll
  for (int e = 0; e < NEXP; ++e) {
#pragma unroll
    for (int s = 32; s > 0; s >>= 1) acc[e] += __shfl_xor(acc[e], s, 64);
  }
  if (lane == 0) {
    float v0 = -1e30f, v1 = -1e30f; int i0 = 0, i1 = 0;
#pragma unroll
    for (int e = 0; e < NEXP; ++e) {
      const float v = acc[e];
      logits[(size_t)t * NEXP + e] = v;
      if (v > v0)      { v1 = v0; i1 = i0; v0 = v; i0 = e; }
      else if (v > v1) { v1 = v; i1 = e; }
    }
    const float g0 = 1.f / (1.f + expf(v1 - v0));  // softmax over top-2
    tki[t * 2] = i0; tki[t * 2 + 1] = i1;
    tkg[t * 2] = g0; tkg[t * 2 + 1] = 1.f - g0;
    atomicAdd(&counts[i0], 1);
    atomicAdd(&counts[i1], 1);
  }
}

__global__ void offsets_kernel(const int* __restrict__ counts, int* __restrict__ off) {
  if (threadIdx.x == 0 && blockIdx.x == 0) {
    int o = 0; off[0] = 0;
    for (int e = 0; e < NEXP; ++e) { o += (counts[e] + ALGN - 1) & ~(ALGN - 1); off[e + 1] = o; }
  }
}

__global__ void scatter_kernel(const int* __restrict__ tki, const float* __restrict__ tkg,
                               const int* __restrict__ off, int* __restrict__ fill,
                               int* __restrict__ ptok, float* __restrict__ pgate,
                               int* __restrict__ inv) {
  const int t = blockIdx.x * 256 + threadIdx.x;
  if (t >= NUM_T) return;
#pragma unroll
  for (int k = 0; k < 2; ++k) {
    const int e = tki[t * 2 + k];
    const int pos = off[e] + atomicAdd(&fill[e], 1);
    ptok[pos] = t;
    pgate[pos] = tkg[t * 2 + k];
    inv[t * 2 + k] = pos;
  }
}

// =====================================================================
// fc GEMM: act = gelu(X[perm] @ Wfc[e]^T), 256x256 tile, BK=64, 8 waves
// 8-phase schedule (T3+T4+T5), 2 K-tiles/iter, counted vmcnt(6) @ P4/P8.
// LDS [buf][A=0/B=1][half][128x64] bf16 = 128 KiB. XOR chunk swizzle (T2).
// Stage slots (derived; every slot staged >=1 barrier after its last read):
//   P1:A1(t1)->buf1  P3:B0(T)->buf0  P4:A0(T)+B1(T)->buf0  P5:A1(T)->buf0
//   P7:B0(T1)->buf1  P8:A0(T1)+B1(T1)->buf1        (T=2i+2, T1=2i+3, clamped)
// =====================================================================
__launch_bounds__(512, 2)
__global__ void fc_gemm(const unsigned short* __restrict__ xb,
                        const unsigned short* __restrict__ wfcb,
                        const int* __restrict__ ptok,
                        const int* __restrict__ off,
                        unsigned short* __restrict__ act) {
  const int nwg = (IDIM / 256) * RB_FC;
  const int wgid = xcd_swz(blockIdx.x, nwg);
  const int row0 = (wgid / (IDIM / 256)) * 256;
  const int icol0 = (wgid % (IDIM / 256)) * 256;
  if (row0 >= off[8]) return;
  int e = 0;
  while (row0 >= off[e + 1]) ++e;

  __shared__ __align__(16) unsigned short L[2][2][2][128 * 64];
  __shared__ int s_tok[256];
  char* Lb = (char*)&L[0][0][0][0];

  const int tid = threadIdx.x;
  if (tid < 256) s_tok[tid] = ptok[row0 + tid];
  __syncthreads();

  // stage sources: load id = ld*512+tid -> row r, pre-swizzled chunk c
  const int r0 = tid >> 3, r1 = (512 + tid) >> 3;
  const int c0 = (((tid) & 7) ^ (r0 & 7)) * 8, c1 = (((512 + tid) & 7) ^ (r1 & 7)) * 8;
  const unsigned short* sA[2][2];
  const unsigned short* sB[2][2];
  sA[0][0] = xb + (size_t)s_tok[r0] * HDIM + c0;
  sA[0][1] = xb + (size_t)s_tok[r1] * HDIM + c1;
  sA[1][0] = xb + (size_t)s_tok[128 + r0] * HDIM + c0;
  sA[1][1] = xb + (size_t)s_tok[128 + r1] * HDIM + c1;
  const size_t wb = (size_t)e * IDIM + icol0;
  sB[0][0] = wfcb + (wb + r0) * HDIM + c0;
  sB[0][1] = wfcb + (wb + r1) * HDIM + c1;
  sB[1][0] = wfcb + (wb + 128 + r0) * HDIM + c0;
  sB[1][1] = wfcb + (wb + 128 + r1) * HDIM + c1;
  const int dst0 = tid * 16, dst1 = (512 + tid) * 16;

#define FC_STAGE_A(bufi, h, tt) do { \
    GL16(sA[h][0] + (tt) * 64, ((bufi) * 4 + (h)) * 16384 + dst0); \
    GL16(sA[h][1] + (tt) * 64, ((bufi) * 4 + (h)) * 16384 + dst1); } while (0)
#define FC_STAGE_B(bufi, h, tt) do { \
    GL16(sB[h][0] + (tt) * 64, ((bufi) * 4 + 2 + (h)) * 16384 + dst0); \
    GL16(sB[h][1] + (tt) * 64, ((bufi) * 4 + 2 + (h)) * 16384 + dst1); } while (0)

  const int lane = tid & 63;
  const int wid = tid >> 6;
  const int wr = wid >> 2;        // 0..1: 128 rows
  const int wc = wid & 3;         // 0..3: 64 cols

  // ds_read byte offsets inside a 16KB half (row*128 + swizzled chunk*16)
  int offA[8], offB[4];
#pragma unroll
  for (int m = 0; m < 8; ++m) {
    const int lr = m * 16 + (lane & 15);
    offA[m] = lr * 128 + (((lane >> 4) ^ (lr & 7)) * 16);
  }
#pragma unroll
  for (int n = 0; n < 4; ++n) {
    const int lr = (wc & 1) * 64 + n * 16 + (lane & 15);
    offB[n] = lr * 128 + (((lane >> 4) ^ (lr & 7)) * 16);
  }
  const char* Ab[2] = { Lb + (0 * 4 + wr) * 16384,          Lb + (1 * 4 + wr) * 16384 };
  const char* Bb[2] = { Lb + (0 * 4 + 2 + (wc >> 1)) * 16384, Lb + (1 * 4 + 2 + (wc >> 1)) * 16384 };

  f32x4 acc[8][4];
#pragma unroll
  for (int m = 0; m < 8; ++m)
#pragma unroll
    for (int n = 0; n < 4; ++n) acc[m][n] = (f32x4){0.f, 0.f, 0.f, 0.f};
  short8 a[4][2], b[2][2][2];

#define FC_LOADA(bufi, mh) do { _Pragma("unroll") \
    for (int mi = 0; mi < 4; ++mi) { \
      a[mi][0] = *(const short8*)(Ab[bufi] + offA[(mh) * 4 + mi]); \
      a[mi][1] = *(const short8*)(Ab[bufi] + (offA[(mh) * 4 + mi] ^ 64)); } } while (0)
#define FC_LOADB(bufi, nh) do { _Pragma("unroll") \
    for (int ni = 0; ni < 2; ++ni) { \
      b[nh][ni][0] = *(const short8*)(Bb[bufi] + offB[(nh) * 2 + ni]); \
      b[nh][ni][1] = *(const short8*)(Bb[bufi] + (offB[(nh) * 2 + ni] ^ 64)); } } while (0)
#define FC_MFMA(mh, nh) do { __builtin_amdgcn_s_setprio(1); _Pragma("unroll") \
    for (int mi = 0; mi < 4; ++mi) { _Pragma("unroll") \
      for (int ni = 0; ni < 2; ++ni) { \
        acc[(mh)*4+mi][(nh)*2+ni] = __builtin_amdgcn_mfma_f32_16x16x32_bf16(a[mi][0], b[nh][ni][0], acc[(mh)*4+mi][(nh)*2+ni], 0, 0, 0); \
        acc[(mh)*4+mi][(nh)*2+ni] = __builtin_amdgcn_mfma_f32_16x16x32_bf16(a[mi][1], b[nh][ni][1], acc[(mh)*4+mi][(nh)*2+ni], 0, 0, 0); } } \
    __builtin_amdgcn_s_setprio(0); } while (0)

  // prologue: tile0 fully + tile1 {A0,B0,B1}; vmcnt(6) leaves tile1's 3 units
  FC_STAGE_A(0, 0, 0); FC_STAGE_B(0, 0, 0); FC_STAGE_B(0, 1, 0); FC_STAGE_A(0, 1, 0);
  FC_STAGE_A(1, 0, 1); FC_STAGE_B(1, 0, 1); FC_STAGE_B(1, 1, 1);
  VMW(6);
  __builtin_amdgcn_s_barrier();

#pragma unroll 1
  for (int i = 0; i < FC_NI; ++i) {
    const int t1 = 2 * i + 1;
    const int T  = (2 * i + 2 < FC_NT) ? 2 * i + 2 : FC_NT - 1;
    const int T1 = (2 * i + 3 < FC_NT) ? 2 * i + 3 : FC_NT - 1;
    // P1: tile t0 (buf0), quadrant (0,0)
    FC_LOADA(0, 0); FC_LOADB(0, 0);
    FC_STAGE_A(1, 1, t1);
    PHASE_SYNC(); FC_MFMA(0, 0); PHASE_END();
    // P2: (0,1)
    FC_LOADB(0, 1);
    PHASE_SYNC(); FC_MFMA(0, 1); PHASE_END();
    // P3: (1,0)
    FC_LOADA(0, 1);
    FC_STAGE_B(0, 0, T);
    PHASE_SYNC(); FC_MFMA(1, 0); PHASE_END();
    // P4: (1,1)
    FC_STAGE_A(0, 0, T); FC_STAGE_B(0, 1, T);
    VMW(6);
    PHASE_SYNC(); FC_MFMA(1, 1); PHASE_END();
    // P5: tile t1 (buf1), (0,0)
    FC_LOADA(1, 0); FC_LOADB(1, 0);
    FC_STAGE_A(0, 1, T);
    PHASE_SYNC(); FC_MFMA(0, 0); PHASE_END();
    // P6: (0,1)
    FC_LOADB(1, 1);
    PHASE_SYNC(); FC_MFMA(0, 1); PHASE_END();
    // P7: (1,0)
    FC_LOADA(1, 1);
    FC_STAGE_B(1, 0, T1);
    PHASE_SYNC(); FC_MFMA(1, 0); PHASE_END();
    // P8: (1,1)
    FC_STAGE_A(1, 0, T1); FC_STAGE_B(1, 1, T1);
    VMW(6);
    PHASE_SYNC(); FC_MFMA(1, 1); PHASE_END();
  }

  // epilogue: exact gelu, bf16 store.  D: row=(lane>>4)*4+r, col=lane&15
#pragma unroll
  for (int m = 0; m < 8; ++m) {
    const int prow = row0 + wr * 128 + m * 16 + (lane >> 4) * 4;
#pragma unroll
    for (int n = 0; n < 4; ++n) {
      const int col = icol0 + wc * 64 + n * 16 + (lane & 15);
#pragma unroll
      for (int r = 0; r < 4; ++r) {
        const float v = acc[m][n][r];
        const float g = 0.5f * v * (1.0f + erff(v * 0.70710678118654752f));
        act[(size_t)(prow + r) * IDIM + col] = f32_to_bf16(g);
      }
    }
  }
#undef FC_STAGE_A
#undef FC_STAGE_B
#undef FC_LOADA
#undef FC_LOADB
#undef FC_MFMA
}

// =====================================================================
// proj GEMM: pair[row] = gate * (act[row] @ Wproj[e]^T), 128x256 tile,
// BK=64, 8 waves (2Mx4N, wave C = 64x64), 4-phase/iter, vmcnt(2) @ P2/P4.
// LDS [buf][unit: A=0,B0=1,B1=2][16KB] = 96 KiB.
// Stages: P1:B0(t1)+B1(t1)->buf1  P2:A(T)->buf0  P3:B0(T)+B1(T)->buf0
//         P4:A(T1)->buf1
// =====================================================================
__launch_bounds__(512, 2)
__global__ void proj_gemm(const unsigned short* __restrict__ actb,
                          const unsigned short* __restrict__ wpb,
                          const float* __restrict__ pgate,
                          const int* __restrict__ off,
                          unsigned short* __restrict__ pair) {
  const int nwg = (HDIM / 256) * RB_PJ;
  const int wgid = xcd_swz(blockIdx.x, nwg);
  const int row0 = (wgid / (HDIM / 256)) * 128;
  const int hcol0 = (wgid % (HDIM / 256)) * 256;
  if (row0 >= off[8]) return;
  int e = 0;
  while (row0 >= off[e + 1]) ++e;

  __shared__ __align__(16) unsigned short L[2][3][128 * 64];
  __shared__ float s_g[128];
  char* Lb = (char*)&L[0][0][0];

  const int tid = threadIdx.x;
  if (tid < 128) s_g[tid] = pgate[row0 + tid];

  const int r0 = tid >> 3, r1 = (512 + tid) >> 3;
  const int c0 = (((tid) & 7) ^ (r0 & 7)) * 8, c1 = (((512 + tid) & 7) ^ (r1 & 7)) * 8;
  const unsigned short* sA[2];
  const unsigned short* sB[2][2];
  sA[0] = actb + (size_t)(row0 + r0) * IDIM + c0;
  sA[1] = actb + (size_t)(row0 + r1) * IDIM + c1;
  const size_t wb = (size_t)e * HDIM + hcol0;
  sB[0][0] = wpb + (wb + r0) * IDIM + c0;
  sB[0][1] = wpb + (wb + r1) * IDIM + c1;
  sB[1][0] = wpb + (wb + 128 + r0) * IDIM + c0;
  sB[1][1] = wpb + (wb + 128 + r1) * IDIM + c1;
  const int dst0 = tid * 16, dst1 = (512 + tid) * 16;

#define PJ_STAGE_A(bufi, tt) do { \
    GL16(sA[0] + (tt) * 64, ((bufi) * 3 + 0) * 16384 + dst0); \
    GL16(sA[1] + (tt) * 64, ((bufi) * 3 + 0) * 16384 + dst1); } while (0)
#define PJ_STAGE_B(bufi, h, tt) do { \
    GL16(sB[h][0] + (tt) * 64, ((bufi) * 3 + 1 + (h)) * 16384 + dst0); \
    GL16(sB[h][1] + (tt) * 64, ((bufi) * 3 + 1 + (h)) * 16384 + dst1); } while (0)

  const int lane = tid & 63;
  const int wid = tid >> 6;
  const int wr = wid >> 2;        // 0..1: 64 rows
  const int wc = wid & 3;         // 0..3: 64 cols

  int offA[4], offB[4];
#pragma unroll
  for (int m = 0; m < 4; ++m) {
    const int lr = wr * 64 + m * 16 + (lane & 15);
    offA[m] = lr * 128 + (((lane >> 4) ^ (lr & 7)) * 16);
  }
#pragma unroll
  for (int n = 0; n < 4; ++n) {
    const int lr = (wc & 1) * 64 + n * 16 + (lane & 15);
    offB[n] = lr * 128 + (((lane >> 4) ^ (lr & 7)) * 16);
  }
  const char* Ab[2] = { Lb, Lb + 3 * 16384 };
  const char* Bb[2] = { Lb + (1 + (wc >> 1)) * 16384, Lb + (3 + 1 + (wc >> 1)) * 16384 };

  f32x4 acc[4][4];
#pragma unroll
  for (int m = 0; m < 4; ++m)
#pragma unroll
    for (int n = 0; n < 4; ++n) acc[m][n] = (f32x4){0.f, 0.f, 0.f, 0.f};
  short8 a[4][2], b[2][2][2];

#define PJ_LOADA(bufi) do { _Pragma("unroll") \
    for (int mi = 0; mi < 4; ++mi) { \
      a[mi][0] = *(const short8*)(Ab[bufi] + offA[mi]); \
      a[mi][1] = *(const short8*)(Ab[bufi] + (offA[mi] ^ 64)); } } while (0)
#define PJ_LOADB(bufi, nh) do { _Pragma("unroll") \
    for (int ni = 0; ni < 2; ++ni) { \
      b[nh][ni][0] = *(const short8*)(Bb[bufi] + offB[(nh) * 2 + ni]); \
      b[nh][ni][1] = *(const short8*)(Bb[bufi] + (offB[(nh) * 2 + ni] ^ 64)); } } while (0)
#define PJ_MFMA(nh) do { __builtin_amdgcn_s_setprio(1); _Pragma("unroll") \
    for (int mi = 0; mi < 4; ++mi) { _Pragma("unroll") \
      for (int ni = 0; ni < 2; ++ni) { \
        acc[mi][(nh)*2+ni] = __builtin_amdgcn_mfma_f32_16x16x32_bf16(a[mi][0], b[nh][ni][0], acc[mi][(nh)*2+ni], 0, 0, 0); \
        acc[mi][(nh)*2+ni] = __builtin_amdgcn_mfma_f32_16x16x32_bf16(a[mi][1], b[nh][ni][1], acc[mi][(nh)*2+ni], 0, 0, 0); } } \
    __builtin_amdgcn_s_setprio(0); } while (0)

  // prologue: A(0),B0(0),B1(0),A(1); vmcnt(2) leaves A(1)
  PJ_STAGE_A(0, 0); PJ_STAGE_B(0, 0, 0); PJ_STAGE_B(0, 1, 0); PJ_STAGE_A(1, 1);
  VMW(2);
  __builtin_amdgcn_s_barrier();

#pragma unroll 1
  for (int i = 0; i < PJ_NI; ++i) {
    const int t1 = 2 * i + 1;
    const int T  = (2 * i + 2 < PJ_NT) ? 2 * i + 2 : PJ_NT - 1;
    const int T1 = (2 * i + 3 < PJ_NT) ? 2 * i + 3 : PJ_NT - 1;
    // P1: tile t0 (buf0), nh=0
    PJ_LOADA(0); PJ_LOADB(0, 0);
    PJ_STAGE_B(1, 0, t1); PJ_STAGE_B(1, 1, t1);
    PHASE_SYNC(); PJ_MFMA(0); PHASE_END();
    // P2: nh=1
    PJ_LOADB(0, 1);
    PJ_STAGE_A(0, T);
    VMW(2);
    PHASE_SYNC(); PJ_MFMA(1); PHASE_END();
    // P3: tile t1 (buf1), nh=0
    PJ_LOADA(1); PJ_LOADB(1, 0);
    PJ_STAGE_B(0, 0, T); PJ_STAGE_B(0, 1, T);
    PHASE_SYNC(); PJ_MFMA(0); PHASE_END();
    // P4: nh=1
    PJ_LOADB(1, 1);
    PJ_STAGE_A(1, T1);
    VMW(2);
    PHASE_SYNC(); PJ_MFMA(1); PHASE_END();
  }

  // epilogue: scale by gate, bf16 store into pair rows (pads have gate 0)
#pragma unroll
  for (int m = 0; m < 4; ++m) {
    const int lr = wr * 64 + m * 16 + (lane >> 4) * 4;
#pragma unroll
    for (int n = 0; n < 4; ++n) {
      const int col = hcol0 + wc * 64 + n * 16 + (lane & 15);
#pragma unroll
      for (int r = 0; r < 4; ++r) {
        const float g = s_g[lr + r];
        pair[(size_t)(row0 + lr + r) * HDIM + col] = f32_to_bf16(g * acc[m][n][r]);
      }
    }
  }
#undef PJ_STAGE_A
#undef PJ_STAGE_B
#undef PJ_LOADA
#undef PJ_LOADB
#undef PJ_MFMA
}

// ---------------- combine: out[t] = pair[inv[t,0]] + pair[inv[t,1]] ----------------
__global__ void combine_kernel(const unsigned short* __restrict__ pair,
                               const int* __restrict__ inv, float* __restrict__ out) {
  const int gid = blockIdx.x * 256 + threadIdx.x;     // NUM_T*HDIM/8 threads
  const int t = gid >> 7;
  const int c8 = (gid & 127) << 3;
  const short8 v0 = *(const short8*)(pair + (size_t)inv[t * 2] * HDIM + c8);
  const short8 v1 = *(const short8*)(pair + (size_t)inv[t * 2 + 1] * HDIM + c8);
  float o[8];
#pragma unroll
  for (int j = 0; j < 8; ++j)
    o[j] = bf16_to_f32((unsigned short)v0[j]) + bf16_to_f32((unsigned short)v1[j]);
  float* dst = out + (size_t)t * HDIM + c8;
  ((float4*)dst)[0] = (float4){o[0], o[1], o[2], o[3]};
  ((float4*)dst)[1] = (float4){o[4], o[5], o[6], o[7]};
}

extern "C" void kernel_launch(void* const* d_in, const int* in_sizes, int n_in,
                              void* d_out, int out_size, void* d_ws, size_t ws_size,
                              hipStream_t stream) {
  const float* x   = (const float*)d_in[0];
  const float* wg  = (const float*)d_in[1];
  const float* wfc = (const float*)d_in[2];
  const float* wpj = (const float*)d_in[3];
  float* out    = (float*)d_out;
  float* logits = out + (size_t)NUM_T * HDIM;

  char* p = (char*)d_ws;
  auto alloc = [&](size_t bytes) { char* q = p; p += (bytes + 255) & ~size_t(255); return q; };
  unsigned short* xb    = (unsigned short*)alloc((size_t)NUM_T * HDIM * 2);
  unsigned short* wfcb  = (unsigned short*)alloc((size_t)NEXP * IDIM * HDIM * 2);
  unsigned short* wpb   = (unsigned short*)alloc((size_t)NEXP * HDIM * IDIM * 2);
  unsigned short* act   = (unsigned short*)alloc((size_t)MAXROWS * IDIM * 2);
  unsigned short* pair  = (unsigned short*)alloc((size_t)MAXROWS * HDIM * 2);
  int*            ptok  = (int*)alloc((size_t)MAXROWS * 4);
  float*          pgate = (float*)alloc((size_t)MAXROWS * 4);
  int*            tki   = (int*)alloc((size_t)NUM_T * 2 * 4);
  float*          tkg   = (float*)alloc((size_t)NUM_T * 2 * 4);
  int*            inv   = (int*)alloc((size_t)NUM_T * 2 * 4);
  int*            counts= (int*)alloc(64);
  int*            fill  = (int*)alloc(64);
  int*            off   = (int*)alloc(64);
  const size_t need = (size_t)(p - (char*)d_ws);
  if (need > ws_size) {
    fprintf(stderr, "kernel_launch: ws too small: need %zu have %zu\n", need, ws_size);
    hipMemsetAsync(d_out, 0, (size_t)out_size * 4, stream);
    return;
  }

  // zero aux region (pads -> token 0 / gate 0; counts/fill for atomics)
  hipMemsetAsync(ptok, 0, (size_t)(p - (char*)ptok), stream);

  cvt_kernel<<<2048, 256, 0, stream>>>(x,   xb,   NUM_T * HDIM / 4);
  cvt_kernel<<<2048, 256, 0, stream>>>(wfc, wfcb, NEXP * IDIM * HDIM / 4);
  cvt_kernel<<<2048, 256, 0, stream>>>(wpj, wpb,  NEXP * HDIM * IDIM / 4);

  router_kernel<<<NUM_T / 4, 256, 0, stream>>>(x, wg, logits, tki, tkg, counts);
  offsets_kernel<<<1, 64, 0, stream>>>(counts, off);
  scatter_kernel<<<NUM_T / 256, 256, 0, stream>>>(tki, tkg, off, fill, ptok, pgate, inv);

  fc_gemm<<<(IDIM / 256) * RB_FC, 512, 0, stream>>>(xb, wfcb, ptok, off, act);
  proj_gemm<<<(HDIM / 256) * RB_PJ, 512, 0, stream>>>(act, wpb, pgate, off, pair);
  combine_kernel<<<NUM_T * HDIM / 8 / 256, 256, 0, stream>>>(pair, inv, out);
}